// Round 1
// baseline (510.150 us; speedup 1.0000x reference)
//
#include <hip/hip_runtime.h>
#include <math.h>

// Problem constants (match reference)
#define B_   16
#define T_   1024
#define F_   512
#define G_   2
#define V_   320
#define D_   128
#define N_   (B_ * T_)      // 16384 tokens
#define GV   (G_ * V_)      // 640
#define EPS_ 1e-7f

// Kernel config
#define ROWS    32          // rows per block
#define THREADS 320         // 5 waves; each thread owns cols (tid, tid+320)
#define NBLK    (N_ / ROWS) // 512 blocks -> exactly 2 blocks/CU resident

// Workspace layout (floats)
#define WS_COUNTS 0                        // T_*G_*V_ = 655360 (zeroed each launch)
#define WS_AVG    (T_ * G_ * V_)           // NBLK*GV  = 327680
#define WS_ENT    (WS_AVG + NBLK * GV)     // T_*G_    = 2048

#define FMA4(a, xv, wv)                                                        \
  a = fmaf(xv.x, wv.x, a); a = fmaf(xv.y, wv.y, a);                            \
  a = fmaf(xv.z, wv.z, a); a = fmaf(xv.w, wv.w, a);

// Fused: GEMM (x @ w^T + b) + softmax stats + argmaxes + codebook gather.
__global__ __launch_bounds__(THREADS) void k_fused(
    const float* __restrict__ x, const float* __restrict__ w,
    const float* __restrict__ bias, const float* __restrict__ cb,
    const float* __restrict__ gum, float* __restrict__ out,
    float* __restrict__ counts, float* __restrict__ avg_part)
{
  __shared__ float lds[ROWS * F_];  // 64 KB: x-tile, then logits tile, then avg staging
  const int tid = threadIdx.x;
  const int blk = blockIdx.x;
  const int n0  = blk * ROWS;

  // ---- stage x tile (32 rows x 512) into LDS, coalesced float4 ----
  {
    const float4* xg = (const float4*)(x + (size_t)n0 * F_);
    float4* xs = (float4*)lds;
    for (int i = tid; i < ROWS * F_ / 4; i += THREADS) xs[i] = xg[i];
  }
  __syncthreads();

  const int c0 = tid;        // group-0 column
  const int c1 = tid + V_;   // group-1 column
  float acc0[ROWS], acc1[ROWS];
#pragma unroll
  for (int r = 0; r < ROWS; ++r) { acc0[r] = 0.f; acc1[r] = 0.f; }

  const float4* w0p = (const float4*)(w + (size_t)c0 * F_);
  const float4* w1p = (const float4*)(w + (size_t)c1 * F_);
  const float4* xs4 = (const float4*)lds;

  // ---- GEMM main loop: 16 k-values per iteration (full 64B w-line per col) ----
  for (int kk = 0; kk < F_ / 16; ++kk) {
    float4 wa0 = w0p[kk * 4 + 0], wa1 = w0p[kk * 4 + 1];
    float4 wa2 = w0p[kk * 4 + 2], wa3 = w0p[kk * 4 + 3];
    float4 wb0 = w1p[kk * 4 + 0], wb1 = w1p[kk * 4 + 1];
    float4 wb2 = w1p[kk * 4 + 2], wb3 = w1p[kk * 4 + 3];
#pragma unroll
    for (int r = 0; r < ROWS; ++r) {
      const float4* xr = xs4 + r * (F_ / 4) + kk * 4;  // wave-uniform -> LDS broadcast
      float4 x0 = xr[0], x1 = xr[1], x2 = xr[2], x3 = xr[3];
      float a0 = acc0[r], a1 = acc1[r];
      FMA4(a0, x0, wa0); FMA4(a0, x1, wa1); FMA4(a0, x2, wa2); FMA4(a0, x3, wa3);
      FMA4(a1, x0, wb0); FMA4(a1, x1, wb1); FMA4(a1, x2, wb2); FMA4(a1, x3, wb3);
      acc0[r] = a0; acc1[r] = a1;
    }
  }

  // ---- phase 2: per-row softmax / argmax / gather, one group at a time ----
  const int wave = tid >> 6;   // 0..4
  const int lane = tid & 63;
  float racc[2][5];            // per-lane softmax-prob partial sums (cols lane+64j)
#pragma unroll
  for (int g = 0; g < 2; ++g)
#pragma unroll
    for (int j = 0; j < 5; ++j) racc[g][j] = 0.f;

#pragma unroll
  for (int g = 0; g < 2; ++g) {
    __syncthreads();  // previous LDS users done
    float* lg = lds;  // logits tile [ROWS][V_]
    const float bc = bias[g * V_ + tid];
#pragma unroll
    for (int r = 0; r < ROWS; ++r)
      lg[r * V_ + tid] = (g == 0 ? acc0[r] : acc1[r]) + bc;
    __syncthreads();

    for (int r = wave; r < ROWS; r += 5) {
      const int n = n0 + r;
      float L[5], GU[5];
#pragma unroll
      for (int j = 0; j < 5; ++j) {
        L[j]  = lg[r * V_ + lane + 64 * j];
        GU[j] = gum[(size_t)n * GV + g * V_ + lane + 64 * j];
      }
      // local max/argmax (first-occurrence tie-break, like jnp.argmax)
      float m1 = L[0];         int a1 = lane;
      float m2 = L[0] + GU[0]; int a2 = lane;
#pragma unroll
      for (int j = 1; j < 5; ++j) {
        const int c = lane + 64 * j;
        if (L[j] > m1) { m1 = L[j]; a1 = c; }
        const float t2 = L[j] + GU[j];
        if (t2 > m2) { m2 = t2; a2 = c; }
      }
      // wave reduce (prefer smaller index on exact ties)
      for (int off = 32; off; off >>= 1) {
        float om = __shfl_down(m1, off); int oa = __shfl_down(a1, off);
        if (om > m1 || (om == m1 && oa < a1)) { m1 = om; a1 = oa; }
        float om2 = __shfl_down(m2, off); int oa2 = __shfl_down(a2, off);
        if (om2 > m2 || (om2 == m2 && oa2 < a2)) { m2 = om2; a2 = oa2; }
      }
      m1 = __shfl(m1, 0); a1 = __shfl(a1, 0); a2 = __shfl(a2, 0);

      // softmax (no tau) for avg_probs
      float e[5], s = 0.f;
#pragma unroll
      for (int j = 0; j < 5; ++j) { e[j] = expf(L[j] - m1); s += e[j]; }
      for (int off = 32; off; off >>= 1) s += __shfl_down(s, off);
      s = __shfl(s, 0);
      const float inv = 1.0f / s;
#pragma unroll
      for (int j = 0; j < 5; ++j) racc[g][j] += e[j] * inv;

      if (lane == 0) {
        const int t = n & (T_ - 1);
        atomicAdd(&counts[(t * G_ + g) * V_ + a1], 1.0f);
      }
      // quantized[n, g*D : (g+1)*D] = codebook[g, a2, :]
      const float2* cbr = (const float2*)(cb + (size_t)(g * V_ + a2) * D_);
      float2* op = (float2*)(out + (size_t)n * (G_ * D_) + g * D_);
      op[lane] = cbr[lane];
    }
  }

  // ---- block-level avg_probs partial: reduce 5 wave-private copies ----
  __syncthreads();
  float* la = lds;  // [5][GV]
#pragma unroll
  for (int g = 0; g < 2; ++g)
#pragma unroll
    for (int j = 0; j < 5; ++j)
      la[wave * GV + g * V_ + lane + 64 * j] = racc[g][j];
  __syncthreads();
  for (int c = tid; c < GV; c += THREADS) {
    float s = 0.f;
#pragma unroll
    for (int wv = 0; wv < 5; ++wv) s += la[wv * GV + c];
    avg_part[(size_t)blk * GV + c] = s;
  }
}

// Per-(t,g) hard-histogram entropy -> exp(-H). One wave per item.
__global__ __launch_bounds__(256) void k_code_ent(
    const float* __restrict__ counts, float* __restrict__ ent)
{
  const int item = blockIdx.x * 4 + (threadIdx.x >> 6);  // 0..2047
  const int lane = threadIdx.x & 63;
  const float* c = counts + (size_t)item * V_;
  float s = 0.f;
#pragma unroll
  for (int j = 0; j < 5; ++j) {
    const float hp = c[lane + 64 * j] * (1.0f / B_);
    s += hp * logf(hp + EPS_);
  }
  for (int off = 32; off; off >>= 1) s += __shfl_down(s, off);
  if (lane == 0) ent[item] = expf(-s);
}

// Finalize both scalars. Single block of 640 threads.
__global__ __launch_bounds__(GV) void k_final(
    const float* __restrict__ avg_part, const float* __restrict__ ent,
    float* __restrict__ out2)
{
  __shared__ float sh[GV];   // p*log(p+eps) per column
  __shared__ float shc[GV];  // code-entropy partials
  const int tid = threadIdx.x;

  float s = 0.f;
  for (int b = 0; b < NBLK; ++b) s += avg_part[(size_t)b * GV + tid];
  const float p = s * (1.0f / N_);
  sh[tid] = p * logf(p + EPS_);

  float cs = 0.f;
  for (int i = tid; i < T_ * G_; i += GV) cs += ent[i];
  shc[tid] = cs;
  __syncthreads();

  if (tid < 64) {
    float s0 = 0.f, s1 = 0.f, sc = 0.f;
    for (int j = tid; j < V_; j += 64) { s0 += sh[j]; s1 += sh[V_ + j]; }
    for (int j = tid; j < GV; j += 64) sc += shc[j];
    for (int off = 32; off; off >>= 1) {
      s0 += __shfl_down(s0, off);
      s1 += __shfl_down(s1, off);
      sc += __shfl_down(sc, off);
    }
    if (tid == 0) {
      out2[0] = sc;                          // code_perplexity
      out2[1] = expf(-s0) + expf(-s1);       // prob_perplexity
    }
  }
}

extern "C" void kernel_launch(void* const* d_in, const int* in_sizes, int n_in,
                              void* d_out, int out_size, void* d_ws, size_t ws_size,
                              hipStream_t stream) {
  const float* x   = (const float*)d_in[0];  // (B,T,F)
  const float* w   = (const float*)d_in[1];  // (G*V, F)
  const float* b   = (const float*)d_in[2];  // (G*V,)
  const float* cb  = (const float*)d_in[3];  // (1, G*V, D)
  const float* gum = (const float*)d_in[4];  // (B*T, G, V)
  float* out = (float*)d_out;                // quantized (N*G*D) ++ [code_ppl, prob_ppl]
  float* ws  = (float*)d_ws;

  float* counts = ws + WS_COUNTS;
  float* avgp   = ws + WS_AVG;
  float* ent    = ws + WS_ENT;

  hipMemsetAsync(counts, 0, (size_t)T_ * G_ * V_ * sizeof(float), stream);
  k_fused<<<NBLK, THREADS, 0, stream>>>(x, w, b, cb, gum, out, counts, avgp);
  k_code_ent<<<(T_ * G_) / 4, 256, 0, stream>>>(counts, ent);
  k_final<<<1, GV, 0, stream>>>(avgp, ent, out + (size_t)N_ * G_ * D_);
}